// Round 11
// baseline (358.515 us; speedup 1.0000x reference)
//
#include <hip/hip_runtime.h>
#include <math.h>

#define T_N 100000
#define H_N 256
#define NT16 (T_N / 16)        // 6250 16-row tiles, exact
#define NB_AT 256              // k_at grid
#define NWAVES (NB_AT * 12)    // 3072 independent waves

typedef __attribute__((ext_vector_type(8))) __bf16 bf16x8;
typedef __attribute__((ext_vector_type(4))) float f32x4;

// ws layout (bytes):
//       0 : WmT bf16 [256][256]   (131072)
//  131072 : proj f32 [256]        (1024)
//  132096 : At   f32 [100000]     (400000)
//  532096 : part2 float2[256]     (2048)
//  536192 : s1g  f32[256]         (1024)
//  537216 : s0g  f32[256]         (1024)
//  538240 : lse  f32              (4)

__device__ __forceinline__ float tanh_fast(float x) {
    float e = __expf(2.0f * x);
    return 1.0f - 2.0f / (e + 1.0f);
}

// ---------------------------------------------------------------- prep
__global__ __launch_bounds__(256) void k_prep(const float* __restrict__ Wm,
                                              const float* __restrict__ hc,
                                              const float* __restrict__ W1,
                                              __bf16* __restrict__ WmT,
                                              float* __restrict__ proj,
                                              float* __restrict__ s1g,
                                              float* __restrict__ s0g) {
    const int j = blockIdx.x;
    const int t = threadIdx.x;
    WmT[j * H_N + t] = (__bf16)Wm[t * H_N + j];   // B^T, k-contiguous
    __shared__ float red[H_N];
    red[t] = hc[t] * W1[j * H_N + t];
    __syncthreads();
    for (int off = 128; off > 0; off >>= 1) {
        if (t < off) red[t] += red[t + off];
        __syncthreads();
    }
    if (t == 0) proj[j] = red[0];
    if (j == 0) { s1g[t] = 0.0f; s0g[t] = 0.0f; }
}

// ---------------------------------------------------------------- fused At + LSE + ct partials
// 768 thr = 12 waves, INDEPENDENT after the B prologue (no main-loop barriers,
// no cross-wave At reduction). Each wave owns whole 16-row tiles: computes all
// 256 cols via j-blocking (acc = one f32x4, tanh-folded per 16-col block into
// pacc), so At rows are wave-complete -> plain stores. B in LDS (128 KB,
// swizzled, loaded once). A-frags direct from global in MFMA layout.
// ct partials from the L2-hot coalesced re-read; LSE online per wave.
__global__ __launch_bounds__(768, 3) void k_at(const float* __restrict__ Mt,
                                               const __bf16* __restrict__ WmT,
                                               const float* __restrict__ proj,
                                               const float* __restrict__ V,
                                               float* __restrict__ At,
                                               float2* __restrict__ part2,
                                               float* __restrict__ s1g,
                                               float* __restrict__ s0g) {
    const int tid = threadIdx.x;
    const int lane = tid & 63;
    const int w = tid >> 6;     // 0..11
    const int l15 = lane & 15;
    const int lg = lane >> 4;   // 0..3

    struct SMem {
        __align__(16) char sB[131072];   // [n=256][k=256] bf16, XOR-swizzled
        float pj[256];
        float vj[256];
        float lsem[12], lses[12];
    };
    __shared__ SMem sm;

    // ---- B prologue (WmT L2-hot after k_prep): 8192 16B-chunks over 768 thr
    for (int g = tid; g < 8192; g += 768) {
        const int n = g >> 5;
        const int c = g & 31;                 // 16B chunk within row
        const bf16x8 v = *(const bf16x8*)(WmT + n * H_N + c * 8);
        *(bf16x8*)(&sm.sB[(n * 512 + c * 16) ^ ((n & 7) << 4)]) = v;
    }
    if (tid < 256) { sm.pj[tid] = proj[tid]; sm.vj[tid] = V[tid]; }
    __syncthreads();   // ONLY barrier before the epilogue

    const int gw = blockIdx.x * 12 + w;   // global wave id
    float lm = -1e30f, ls = 0.0f;
    float s1a[4] = {0.f, 0.f, 0.f, 0.f};
    float s0a[4] = {0.f, 0.f, 0.f, 0.f};

    for (int tile = gw; tile < NT16; tile += NWAVES) {
        const float* arow = Mt + (size_t)(tile * 16 + l15) * H_N;

        // ---- A fragments straight from global (row l15, k = 32ks+8lg..+8)
        bf16x8 af[8];
#pragma unroll
        for (int ks = 0; ks < 8; ++ks) {
            const float4 a0 = *(const float4*)(arow + 32 * ks + 8 * lg);
            const float4 a1 = *(const float4*)(arow + 32 * ks + 8 * lg + 4);
            af[ks][0] = (__bf16)a0.x; af[ks][1] = (__bf16)a0.y;
            af[ks][2] = (__bf16)a0.z; af[ks][3] = (__bf16)a0.w;
            af[ks][4] = (__bf16)a1.x; af[ks][5] = (__bf16)a1.y;
            af[ks][6] = (__bf16)a1.z; af[ks][7] = (__bf16)a1.w;
        }

        // ---- j-blocked MFMA: 16 col-blocks of 16; acc freed each block
        float pacc[4] = {0.f, 0.f, 0.f, 0.f};
#pragma unroll
        for (int jb = 0; jb < 16; ++jb) {
            f32x4 acc = {0.f, 0.f, 0.f, 0.f};
            const int n = 16 * jb + l15;
            const int nb = n * 512;
            const int nswz = (n & 7) << 4;
#pragma unroll
            for (int ks = 0; ks < 8; ++ks) {
                const bf16x8 bf = *(const bf16x8*)(
                    &sm.sB[nb + (((32 * ks + 8 * lg) * 2) ^ nswz)]);
                acc = __builtin_amdgcn_mfma_f32_16x16x32_bf16(af[ks], bf, acc, 0, 0, 0);
            }
            const float pjv = sm.pj[n], vjv = sm.vj[n];
#pragma unroll
            for (int i = 0; i < 4; ++i)
                pacc[i] += tanh_fast(acc[i] + pjv) * vjv;
        }

        // ---- row sums: butterfly over the 16 lanes of each lg group
        float p[4];
#pragma unroll
        for (int i = 0; i < 4; ++i) {
            float q = pacc[i];
            q += __shfl_xor(q, 1);
            q += __shfl_xor(q, 2);
            q += __shfl_xor(q, 4);
            q += __shfl_xor(q, 8);
            p[i] = q;    // all lanes in group hold row (4lg+i) total
        }
        if (l15 == 0) {
#pragma unroll
            for (int i = 0; i < 4; ++i) {
                const float at = p[i];
                At[tile * 16 + 4 * lg + i] = at;
                if (at > lm) { ls = ls * __expf(lm - at) + 1.0f; lm = at; }
                else ls += __expf(at - lm);
            }
        }

        // ---- ct partials: coalesced re-read of the (L2-hot) fp32 tile
        const float* crow = Mt + (size_t)tile * 16 * H_N + lane * 4;
#pragma unroll
        for (int r = 0; r < 16; ++r) {
            const float atr = __shfl(p[r & 3], 16 * (r >> 2));
            const float4 x = *(const float4*)(crow + (size_t)r * H_N);
            s1a[0] += atr * x.x; s1a[1] += atr * x.y;
            s1a[2] += atr * x.z; s1a[3] += atr * x.w;
            s0a[0] += x.x; s0a[1] += x.y;
            s0a[2] += x.z; s0a[3] += x.w;
        }
    }

    // ---- wave LSE partial -> shared; block combine by thread 0
#pragma unroll
    for (int d = 1; d < 64; d <<= 1) {
        const float m2 = __shfl_xor(lm, d), s2 = __shfl_xor(ls, d);
        const float M = fmaxf(lm, m2);
        ls = ls * __expf(lm - M) + s2 * __expf(m2 - M);
        lm = M;
    }
    if (lane == 0) { sm.lsem[w] = lm; sm.lses[w] = ls; }

    // ---- block reduce of ct partials (reuse sB region)
    __syncthreads();
    float* red1 = (float*)&sm.sB[0];       // [12][256]
    float* red2 = (float*)&sm.sB[16384];   // [12][256]
#pragma unroll
    for (int q = 0; q < 4; ++q) {
        red1[w * 256 + lane * 4 + q] = s1a[q];
        red2[w * 256 + lane * 4 + q] = s0a[q];
    }
    __syncthreads();
    if (tid < 256) {
        float a = 0.f;
#pragma unroll
        for (int g = 0; g < 12; ++g) a += red1[g * 256 + tid];
        atomicAdd(&s1g[tid], a);
    } else if (tid < 512) {
        const int c = tid - 256;
        float a = 0.f;
#pragma unroll
        for (int g = 0; g < 12; ++g) a += red2[g * 256 + c];
        atomicAdd(&s0g[c], a);
    } else if (tid == 512) {
        float m = sm.lsem[0], s = sm.lses[0];
#pragma unroll
        for (int g = 1; g < 12; ++g) {
            const float m2 = sm.lsem[g], s2 = sm.lses[g];
            const float M = fmaxf(m, m2);
            s = s * __expf(m - M) + s2 * __expf(m2 - M);
            m = M;
        }
        part2[blockIdx.x] = make_float2(m, s);
    }
}

// ---------------------------------------------------------------- final: LSE + ct
__global__ __launch_bounds__(256) void k_final(const float2* __restrict__ part2,
                                               const float* __restrict__ s1g,
                                               const float* __restrict__ s0g,
                                               float* __restrict__ lse,
                                               float* __restrict__ out) {
    const int tid = threadIdx.x;
    __shared__ float ms[256], ss[256];
    const float2 p = part2[tid];
    ms[tid] = p.x; ss[tid] = p.y;
    __syncthreads();
    for (int off = 128; off > 0; off >>= 1) {
        if (tid < off) {
            const float m2 = ms[tid + off], s2 = ss[tid + off];
            const float M = fmaxf(ms[tid], m2);
            ss[tid] = ss[tid] * __expf(ms[tid] - M) + s2 * __expf(m2 - M);
            ms[tid] = M;
        }
        __syncthreads();
    }
    __shared__ float Ls;
    if (tid == 0) { Ls = ms[0] + logf(ss[0]); *lse = Ls; }
    __syncthreads();
    out[T_N + tid] = s1g[tid] - Ls * s0g[tid];
}

// ---------------------------------------------------------------- alphat = At - LSE
__global__ __launch_bounds__(256) void k_alpha(const float* __restrict__ At,
                                               const float* __restrict__ lse,
                                               float* __restrict__ out) {
    const float L = *lse;
    const int i4 = blockIdx.x * 256 + threadIdx.x;
    if (i4 < T_N / 4) {
        float4 a = *(const float4*)(At + i4 * 4);
        a.x -= L; a.y -= L; a.z -= L; a.w -= L;
        *(float4*)(out + i4 * 4) = a;
    }
}

// ----------------------------------------------------------------
extern "C" void kernel_launch(void* const* d_in, const int* in_sizes, int n_in,
                              void* d_out, int out_size, void* d_ws, size_t ws_size,
                              hipStream_t stream) {
    const float* inputs = (const float*)d_in[0];  // (T, H)
    const float* hc     = (const float*)d_in[1];  // (1, H)
    const float* Wm     = (const float*)d_in[2];  // (H, H)
    const float* V      = (const float*)d_in[3];  // (H, 1)
    const float* W1     = (const float*)d_in[4];  // (H, H)
    float* out = (float*)d_out;                   // [alphat (T) | ct (H)]

    char* ws = (char*)d_ws;
    __bf16* WmT  = (__bf16*)ws;
    float* proj  = (float*)(ws + 131072);
    float* At    = (float*)(ws + 132096);
    float2* p2   = (float2*)(ws + 532096);
    float* s1g   = (float*)(ws + 536192);
    float* s0g   = (float*)(ws + 537216);
    float* lse   = (float*)(ws + 538240);

    k_prep<<<256, 256, 0, stream>>>(Wm, hc, W1, WmT, proj, s1g, s0g);
    k_at<<<NB_AT, 768, 0, stream>>>(inputs, WmT, proj, V, At, p2, s1g, s0g);
    k_final<<<1, 256, 0, stream>>>(p2, s1g, s0g, lse, out);
    k_alpha<<<98, 256, 0, stream>>>(At, lse, out);
}

// Round 12
// 68.585 us; speedup vs baseline: 5.2273x; 5.2273x over previous
//
#include <hip/hip_runtime.h>
#include <math.h>

#define T_N 100000
#define H_N 256
#define NT16 (T_N / 16)        // 6250 16-row tiles, exact
#define NB_AT 256              // k_at grid
#define NWAVES (NB_AT * 12)    // 3072 independent waves

typedef __attribute__((ext_vector_type(8))) __bf16 bf16x8;
typedef __attribute__((ext_vector_type(4))) float f32x4;

// ws layout (bytes):
//       0 : WmT bf16 [256][256]   (131072)
//  131072 : proj f32 [256]        (1024)
//  132096 : At   f32 [100000]     (400000)
//  532096 : part2 float2[256]     (2048)
//  536192 : s1g  f32[256]         (1024)
//  537216 : s0g  f32[256]         (1024)
//  538240 : lse  f32              (4)

__device__ __forceinline__ float tanh_fast(float x) {
    float e = __expf(2.0f * x);
    return 1.0f - 2.0f / (e + 1.0f);
}

// ---------------------------------------------------------------- prep
__global__ __launch_bounds__(256) void k_prep(const float* __restrict__ Wm,
                                              const float* __restrict__ hc,
                                              const float* __restrict__ W1,
                                              __bf16* __restrict__ WmT,
                                              float* __restrict__ proj,
                                              float* __restrict__ s1g,
                                              float* __restrict__ s0g) {
    const int j = blockIdx.x;
    const int t = threadIdx.x;
    WmT[j * H_N + t] = (__bf16)Wm[t * H_N + j];   // B^T, k-contiguous
    __shared__ float red[H_N];
    red[t] = hc[t] * W1[j * H_N + t];
    __syncthreads();
    for (int off = 128; off > 0; off >>= 1) {
        if (t < off) red[t] += red[t + off];
        __syncthreads();
    }
    if (t == 0) proj[j] = red[0];
    if (j == 0) { s1g[t] = 0.0f; s0g[t] = 0.0f; }
}

// ---------------------------------------------------------------- fused At + LSE + ct partials
// 768 thr = 12 INDEPENDENT waves (no main-loop barriers). Each wave owns whole
// 16-row tiles; all 256 cols via j-blocking with #pragma unroll 1 (ONE acc
// chain live -> no register explosion, no spill). B in LDS once (swizzled).
// A-frags direct from global in MFMA layout; ct partials from the L2-hot
// coalesced fp32 re-read; LSE online per wave.
__global__ __launch_bounds__(768, 2) void k_at(const float* __restrict__ Mt,
                                               const __bf16* __restrict__ WmT,
                                               const float* __restrict__ proj,
                                               const float* __restrict__ V,
                                               float* __restrict__ At,
                                               float2* __restrict__ part2,
                                               float* __restrict__ s1g,
                                               float* __restrict__ s0g) {
    const int tid = threadIdx.x;
    const int lane = tid & 63;
    const int w = tid >> 6;     // 0..11
    const int l15 = lane & 15;
    const int lg = lane >> 4;   // 0..3

    struct SMem {
        __align__(16) char sB[131072];   // [n=256][k=256] bf16, XOR-swizzled
        float pj[256];
        float vj[256];
        float lsem[12], lses[12];
    };
    __shared__ SMem sm;

    // ---- B prologue (WmT L2-hot after k_prep)
    for (int g = tid; g < 8192; g += 768) {
        const int n = g >> 5;
        const int c = g & 31;
        const bf16x8 v = *(const bf16x8*)(WmT + n * H_N + c * 8);
        *(bf16x8*)(&sm.sB[(n * 512 + c * 16) ^ ((n & 7) << 4)]) = v;
    }
    if (tid < 256) { sm.pj[tid] = proj[tid]; sm.vj[tid] = V[tid]; }
    __syncthreads();   // ONLY barrier before the epilogue

    const int gw = blockIdx.x * 12 + w;   // global wave id
    float lm = -1e30f, ls = 0.0f;
    float s1a[4] = {0.f, 0.f, 0.f, 0.f};
    float s0a[4] = {0.f, 0.f, 0.f, 0.f};

    for (int tile = gw; tile < NT16; tile += NWAVES) {
        const float* arow = Mt + (size_t)(tile * 16 + l15) * H_N;

        // ---- A fragments straight from global (row l15, k = 32ks+8lg..+8)
        bf16x8 af[8];
#pragma unroll
        for (int ks = 0; ks < 8; ++ks) {
            const float4 a0 = *(const float4*)(arow + 32 * ks + 8 * lg);
            const float4 a1 = *(const float4*)(arow + 32 * ks + 8 * lg + 4);
            af[ks][0] = (__bf16)a0.x; af[ks][1] = (__bf16)a0.y;
            af[ks][2] = (__bf16)a0.z; af[ks][3] = (__bf16)a0.w;
            af[ks][4] = (__bf16)a1.x; af[ks][5] = (__bf16)a1.y;
            af[ks][6] = (__bf16)a1.z; af[ks][7] = (__bf16)a1.w;
        }

        // ---- j-blocked MFMA: 16 col-blocks of 16, ONE chain at a time
        float pacc[4] = {0.f, 0.f, 0.f, 0.f};
#pragma unroll 1
        for (int jb = 0; jb < 16; ++jb) {
            f32x4 acc = {0.f, 0.f, 0.f, 0.f};
            const int n = 16 * jb + l15;
            const int nb = n * 512;
            const int nswz = (n & 7) << 4;
#pragma unroll
            for (int ks = 0; ks < 8; ++ks) {
                const bf16x8 bf = *(const bf16x8*)(
                    &sm.sB[nb + (((32 * ks + 8 * lg) * 2) ^ nswz)]);
                acc = __builtin_amdgcn_mfma_f32_16x16x32_bf16(af[ks], bf, acc, 0, 0, 0);
            }
            const float pjv = sm.pj[n], vjv = sm.vj[n];
#pragma unroll
            for (int i = 0; i < 4; ++i)
                pacc[i] += tanh_fast(acc[i] + pjv) * vjv;
        }

        // ---- row sums: butterfly over the 16 lanes of each lg group
        float p[4];
#pragma unroll
        for (int i = 0; i < 4; ++i) {
            float q = pacc[i];
            q += __shfl_xor(q, 1);
            q += __shfl_xor(q, 2);
            q += __shfl_xor(q, 4);
            q += __shfl_xor(q, 8);
            p[i] = q;    // all lanes in group hold row (4lg+i) total
        }
        if (l15 == 0) {
#pragma unroll
            for (int i = 0; i < 4; ++i) {
                const float at = p[i];
                At[tile * 16 + 4 * lg + i] = at;
                if (at > lm) { ls = ls * __expf(lm - at) + 1.0f; lm = at; }
                else ls += __expf(at - lm);
            }
        }

        // ---- ct partials: coalesced re-read of the (L2-hot) fp32 tile
        const float* crow = Mt + (size_t)tile * 16 * H_N + lane * 4;
#pragma unroll 1
        for (int r = 0; r < 16; ++r) {
            const float atr = __shfl(p[r & 3], 16 * (r >> 2));
            const float4 x = *(const float4*)(crow + (size_t)r * H_N);
            s1a[0] += atr * x.x; s1a[1] += atr * x.y;
            s1a[2] += atr * x.z; s1a[3] += atr * x.w;
            s0a[0] += x.x; s0a[1] += x.y;
            s0a[2] += x.z; s0a[3] += x.w;
        }
    }

    // ---- wave LSE partial -> shared
#pragma unroll
    for (int d = 1; d < 64; d <<= 1) {
        const float m2 = __shfl_xor(lm, d), s2 = __shfl_xor(ls, d);
        const float M = fmaxf(lm, m2);
        ls = ls * __expf(lm - M) + s2 * __expf(m2 - M);
        lm = M;
    }
    if (lane == 0) { sm.lsem[w] = lm; sm.lses[w] = ls; }

    // ---- block reduce of ct partials (reuse sB region)
    __syncthreads();
    float* red1 = (float*)&sm.sB[0];       // [12][256]
    float* red2 = (float*)&sm.sB[16384];   // [12][256]
#pragma unroll
    for (int q = 0; q < 4; ++q) {
        red1[w * 256 + lane * 4 + q] = s1a[q];
        red2[w * 256 + lane * 4 + q] = s0a[q];
    }
    __syncthreads();
    if (tid < 256) {
        float a = 0.f;
#pragma unroll
        for (int g = 0; g < 12; ++g) a += red1[g * 256 + tid];
        atomicAdd(&s1g[tid], a);
    } else if (tid < 512) {
        const int c = tid - 256;
        float a = 0.f;
#pragma unroll
        for (int g = 0; g < 12; ++g) a += red2[g * 256 + c];
        atomicAdd(&s0g[c], a);
    } else if (tid == 512) {
        float m = sm.lsem[0], s = sm.lses[0];
#pragma unroll
        for (int g = 1; g < 12; ++g) {
            const float m2 = sm.lsem[g], s2 = sm.lses[g];
            const float M = fmaxf(m, m2);
            s = s * __expf(m - M) + s2 * __expf(m2 - M);
            m = M;
        }
        part2[blockIdx.x] = make_float2(m, s);
    }
}

// ---------------------------------------------------------------- final: LSE + ct
__global__ __launch_bounds__(256) void k_final(const float2* __restrict__ part2,
                                               const float* __restrict__ s1g,
                                               const float* __restrict__ s0g,
                                               float* __restrict__ lse,
                                               float* __restrict__ out) {
    const int tid = threadIdx.x;
    __shared__ float ms[256], ss[256];
    const float2 p = part2[tid];
    ms[tid] = p.x; ss[tid] = p.y;
    __syncthreads();
    for (int off = 128; off > 0; off >>= 1) {
        if (tid < off) {
            const float m2 = ms[tid + off], s2 = ss[tid + off];
            const float M = fmaxf(ms[tid], m2);
            ss[tid] = ss[tid] * __expf(ms[tid] - M) + s2 * __expf(m2 - M);
            ms[tid] = M;
        }
        __syncthreads();
    }
    __shared__ float Ls;
    if (tid == 0) { Ls = ms[0] + logf(ss[0]); *lse = Ls; }
    __syncthreads();
    out[T_N + tid] = s1g[tid] - Ls * s0g[tid];
}

// ---------------------------------------------------------------- alphat = At - LSE
__global__ __launch_bounds__(256) void k_alpha(const float* __restrict__ At,
                                               const float* __restrict__ lse,
                                               float* __restrict__ out) {
    const float L = *lse;
    const int i4 = blockIdx.x * 256 + threadIdx.x;
    if (i4 < T_N / 4) {
        float4 a = *(const float4*)(At + i4 * 4);
        a.x -= L; a.y -= L; a.z -= L; a.w -= L;
        *(float4*)(out + i4 * 4) = a;
    }
}

// ----------------------------------------------------------------
extern "C" void kernel_launch(void* const* d_in, const int* in_sizes, int n_in,
                              void* d_out, int out_size, void* d_ws, size_t ws_size,
                              hipStream_t stream) {
    const float* inputs = (const float*)d_in[0];  // (T, H)
    const float* hc     = (const float*)d_in[1];  // (1, H)
    const float* Wm     = (const float*)d_in[2];  // (H, H)
    const float* V      = (const float*)d_in[3];  // (H, 1)
    const float* W1     = (const float*)d_in[4];  // (H, H)
    float* out = (float*)d_out;                   // [alphat (T) | ct (H)]

    char* ws = (char*)d_ws;
    __bf16* WmT  = (__bf16*)ws;
    float* proj  = (float*)(ws + 131072);
    float* At    = (float*)(ws + 132096);
    float2* p2   = (float2*)(ws + 532096);
    float* s1g   = (float*)(ws + 536192);
    float* s0g   = (float*)(ws + 537216);
    float* lse   = (float*)(ws + 538240);

    k_prep<<<256, 256, 0, stream>>>(Wm, hc, W1, WmT, proj, s1g, s0g);
    k_at<<<NB_AT, 768, 0, stream>>>(inputs, WmT, proj, V, At, p2, s1g, s0g);
    k_final<<<1, 256, 0, stream>>>(p2, s1g, s0g, lse, out);
    k_alpha<<<98, 256, 0, stream>>>(At, lse, out);
}

// Round 13
// 60.904 us; speedup vs baseline: 5.8866x; 1.1261x over previous
//
#include <hip/hip_runtime.h>
#include <math.h>

#define T_N 100000
#define H_N 256
#define NT16 (T_N / 16)        // 6250 16-row tiles, exact
#define NB_AT 256              // k_at grid
#define NWAVES (NB_AT * 12)    // 3072 independent waves

typedef __attribute__((ext_vector_type(8))) __bf16 bf16x8;
typedef __attribute__((ext_vector_type(4))) float f32x4;

// ws layout (bytes):
//       0 : WmT bf16 [256][256]   (131072)
//  131072 : proj f32 [256]        (1024)
//  132096 : At   f32 [100000]     (400000)
//  532096 : part2 float2[256]     (2048)
//  536192 : s1g  f32[256]         (1024)
//  537216 : s0g  f32[256]         (1024)
//  538240 : lse  f32              (4)

__device__ __forceinline__ float tanh_fast(float x) {
    float e = __expf(2.0f * x);
    return 1.0f - 2.0f / (e + 1.0f);
}

// ---------------------------------------------------------------- prep
__global__ __launch_bounds__(256) void k_prep(const float* __restrict__ Wm,
                                              const float* __restrict__ hc,
                                              const float* __restrict__ W1,
                                              __bf16* __restrict__ WmT,
                                              float* __restrict__ proj,
                                              float* __restrict__ s1g,
                                              float* __restrict__ s0g) {
    const int j = blockIdx.x;
    const int t = threadIdx.x;
    WmT[j * H_N + t] = (__bf16)Wm[t * H_N + j];   // B^T, k-contiguous
    __shared__ float red[H_N];
    red[t] = hc[t] * W1[j * H_N + t];
    __syncthreads();
    for (int off = 128; off > 0; off >>= 1) {
        if (t < off) red[t] += red[t + off];
        __syncthreads();
    }
    if (t == 0) proj[j] = red[0];
    if (j == 0) { s1g[t] = 0.0f; s0g[t] = 0.0f; }
}

// ---------------------------------------------------------------- fused At + LSE + ct partials
// 768 thr = 12 INDEPENDENT waves (no main-loop barriers). Each wave owns whole
// 16-row tiles; 256 cols via j-blocking (#pragma unroll 2 -> two acc chains,
// ds_read latency hidden under MFMA chain). ct partials: all 16 fp32 row-chunks
// loaded UPFRONT (one latency exposure, regs freed from af[]), then FMA.
__global__ __launch_bounds__(768, 2) void k_at(const float* __restrict__ Mt,
                                               const __bf16* __restrict__ WmT,
                                               const float* __restrict__ proj,
                                               const float* __restrict__ V,
                                               float* __restrict__ At,
                                               float2* __restrict__ part2,
                                               float* __restrict__ s1g,
                                               float* __restrict__ s0g) {
    const int tid = threadIdx.x;
    const int lane = tid & 63;
    const int w = tid >> 6;     // 0..11
    const int l15 = lane & 15;
    const int lg = lane >> 4;   // 0..3

    struct SMem {
        __align__(16) char sB[131072];   // [n=256][k=256] bf16, XOR-swizzled
        float pj[256];
        float vj[256];
        float lsem[12], lses[12];
    };
    __shared__ SMem sm;

    // ---- B prologue (WmT L2-hot after k_prep)
    for (int g = tid; g < 8192; g += 768) {
        const int n = g >> 5;
        const int c = g & 31;
        const bf16x8 v = *(const bf16x8*)(WmT + n * H_N + c * 8);
        *(bf16x8*)(&sm.sB[(n * 512 + c * 16) ^ ((n & 7) << 4)]) = v;
    }
    if (tid < 256) { sm.pj[tid] = proj[tid]; sm.vj[tid] = V[tid]; }
    __syncthreads();   // ONLY barrier before the epilogue

    const int gw = blockIdx.x * 12 + w;   // global wave id
    float lm = -1e30f, ls = 0.0f;
    float s1a[4] = {0.f, 0.f, 0.f, 0.f};
    float s0a[4] = {0.f, 0.f, 0.f, 0.f};

    for (int tile = gw; tile < NT16; tile += NWAVES) {
        const float* arow = Mt + (size_t)(tile * 16 + l15) * H_N;

        // ---- A fragments straight from global (row l15, k = 32ks+8lg..+8)
        bf16x8 af[8];
#pragma unroll
        for (int ks = 0; ks < 8; ++ks) {
            const float4 a0 = *(const float4*)(arow + 32 * ks + 8 * lg);
            const float4 a1 = *(const float4*)(arow + 32 * ks + 8 * lg + 4);
            af[ks][0] = (__bf16)a0.x; af[ks][1] = (__bf16)a0.y;
            af[ks][2] = (__bf16)a0.z; af[ks][3] = (__bf16)a0.w;
            af[ks][4] = (__bf16)a1.x; af[ks][5] = (__bf16)a1.y;
            af[ks][6] = (__bf16)a1.z; af[ks][7] = (__bf16)a1.w;
        }

        // ---- j-blocked MFMA: 16 col-blocks of 16, TWO chains in flight
        float pacc[4] = {0.f, 0.f, 0.f, 0.f};
#pragma unroll 2
        for (int jb = 0; jb < 16; ++jb) {
            f32x4 acc = {0.f, 0.f, 0.f, 0.f};
            const int n = 16 * jb + l15;
            const int nb = n * 512;
            const int nswz = (n & 7) << 4;
#pragma unroll
            for (int ks = 0; ks < 8; ++ks) {
                const bf16x8 bf = *(const bf16x8*)(
                    &sm.sB[nb + (((32 * ks + 8 * lg) * 2) ^ nswz)]);
                acc = __builtin_amdgcn_mfma_f32_16x16x32_bf16(af[ks], bf, acc, 0, 0, 0);
            }
            const float pjv = sm.pj[n], vjv = sm.vj[n];
#pragma unroll
            for (int i = 0; i < 4; ++i)
                pacc[i] += tanh_fast(acc[i] + pjv) * vjv;
        }

        // ---- row sums: butterfly over the 16 lanes of each lg group
        float p[4];
#pragma unroll
        for (int i = 0; i < 4; ++i) {
            float q = pacc[i];
            q += __shfl_xor(q, 1);
            q += __shfl_xor(q, 2);
            q += __shfl_xor(q, 4);
            q += __shfl_xor(q, 8);
            p[i] = q;    // all lanes in group hold row (4lg+i) total
        }
        if (l15 == 0) {
#pragma unroll
            for (int i = 0; i < 4; ++i) {
                const float at = p[i];
                At[tile * 16 + 4 * lg + i] = at;
                if (at > lm) { ls = ls * __expf(lm - at) + 1.0f; lm = at; }
                else ls += __expf(at - lm);
            }
        }

        // ---- ct partials: all 16 row-chunks loaded upfront (af[] now dead,
        //      regs reused), single latency exposure, then pure FMA
        const float* crow = Mt + (size_t)tile * 16 * H_N + lane * 4;
        float4 x[16];
#pragma unroll
        for (int r = 0; r < 16; ++r)
            x[r] = *(const float4*)(crow + (size_t)r * H_N);
#pragma unroll
        for (int r = 0; r < 16; ++r) {
            const float atr = __shfl(p[r & 3], 16 * (r >> 2));
            s1a[0] += atr * x[r].x; s1a[1] += atr * x[r].y;
            s1a[2] += atr * x[r].z; s1a[3] += atr * x[r].w;
            s0a[0] += x[r].x; s0a[1] += x[r].y;
            s0a[2] += x[r].z; s0a[3] += x[r].w;
        }
    }

    // ---- wave LSE partial -> shared
#pragma unroll
    for (int d = 1; d < 64; d <<= 1) {
        const float m2 = __shfl_xor(lm, d), s2 = __shfl_xor(ls, d);
        const float M = fmaxf(lm, m2);
        ls = ls * __expf(lm - M) + s2 * __expf(m2 - M);
        lm = M;
    }
    if (lane == 0) { sm.lsem[w] = lm; sm.lses[w] = ls; }

    // ---- block reduce of ct partials (reuse sB region)
    __syncthreads();
    float* red1 = (float*)&sm.sB[0];       // [12][256]
    float* red2 = (float*)&sm.sB[16384];   // [12][256]
#pragma unroll
    for (int q = 0; q < 4; ++q) {
        red1[w * 256 + lane * 4 + q] = s1a[q];
        red2[w * 256 + lane * 4 + q] = s0a[q];
    }
    __syncthreads();
    if (tid < 256) {
        float a = 0.f;
#pragma unroll
        for (int g = 0; g < 12; ++g) a += red1[g * 256 + tid];
        atomicAdd(&s1g[tid], a);
    } else if (tid < 512) {
        const int c = tid - 256;
        float a = 0.f;
#pragma unroll
        for (int g = 0; g < 12; ++g) a += red2[g * 256 + c];
        atomicAdd(&s0g[c], a);
    } else if (tid == 512) {
        float m = sm.lsem[0], s = sm.lses[0];
#pragma unroll
        for (int g = 1; g < 12; ++g) {
            const float m2 = sm.lsem[g], s2 = sm.lses[g];
            const float M = fmaxf(m, m2);
            s = s * __expf(m - M) + s2 * __expf(m2 - M);
            m = M;
        }
        part2[blockIdx.x] = make_float2(m, s);
    }
}

// ---------------------------------------------------------------- final: LSE + ct
__global__ __launch_bounds__(256) void k_final(const float2* __restrict__ part2,
                                               const float* __restrict__ s1g,
                                               const float* __restrict__ s0g,
                                               float* __restrict__ lse,
                                               float* __restrict__ out) {
    const int tid = threadIdx.x;
    __shared__ float ms[256], ss[256];
    const float2 p = part2[tid];
    ms[tid] = p.x; ss[tid] = p.y;
    __syncthreads();
    for (int off = 128; off > 0; off >>= 1) {
        if (tid < off) {
            const float m2 = ms[tid + off], s2 = ss[tid + off];
            const float M = fmaxf(ms[tid], m2);
            ss[tid] = ss[tid] * __expf(ms[tid] - M) + s2 * __expf(m2 - M);
            ms[tid] = M;
        }
        __syncthreads();
    }
    __shared__ float Ls;
    if (tid == 0) { Ls = ms[0] + logf(ss[0]); *lse = Ls; }
    __syncthreads();
    out[T_N + tid] = s1g[tid] - Ls * s0g[tid];
}

// ---------------------------------------------------------------- alphat = At - LSE
__global__ __launch_bounds__(256) void k_alpha(const float* __restrict__ At,
                                               const float* __restrict__ lse,
                                               float* __restrict__ out) {
    const float L = *lse;
    const int i4 = blockIdx.x * 256 + threadIdx.x;
    if (i4 < T_N / 4) {
        float4 a = *(const float4*)(At + i4 * 4);
        a.x -= L; a.y -= L; a.z -= L; a.w -= L;
        *(float4*)(out + i4 * 4) = a;
    }
}

// ----------------------------------------------------------------
extern "C" void kernel_launch(void* const* d_in, const int* in_sizes, int n_in,
                              void* d_out, int out_size, void* d_ws, size_t ws_size,
                              hipStream_t stream) {
    const float* inputs = (const float*)d_in[0];  // (T, H)
    const float* hc     = (const float*)d_in[1];  // (1, H)
    const float* Wm     = (const float*)d_in[2];  // (H, H)
    const float* V      = (const float*)d_in[3];  // (H, 1)
    const float* W1     = (const float*)d_in[4];  // (H, H)
    float* out = (float*)d_out;                   // [alphat (T) | ct (H)]

    char* ws = (char*)d_ws;
    __bf16* WmT  = (__bf16*)ws;
    float* proj  = (float*)(ws + 131072);
    float* At    = (float*)(ws + 132096);
    float2* p2   = (float2*)(ws + 532096);
    float* s1g   = (float*)(ws + 536192);
    float* s0g   = (float*)(ws + 537216);
    float* lse   = (float*)(ws + 538240);

    k_prep<<<256, 256, 0, stream>>>(Wm, hc, W1, WmT, proj, s1g, s0g);
    k_at<<<NB_AT, 768, 0, stream>>>(inputs, WmT, proj, V, At, p2, s1g, s0g);
    k_final<<<1, 256, 0, stream>>>(p2, s1g, s0g, lse, out);
    k_alpha<<<98, 256, 0, stream>>>(At, lse, out);
}

// Round 14
// 59.569 us; speedup vs baseline: 6.0185x; 1.0224x over previous
//
#include <hip/hip_runtime.h>
#include <math.h>

#define T_N 100000
#define H_N 256
#define NT16 (T_N / 16)        // 6250 16-row tiles, exact
#define NB_AT 256              // k_at grid
#define NWAVES (NB_AT * 12)    // 3072 independent waves

typedef __attribute__((ext_vector_type(8))) __bf16 bf16x8;
typedef __attribute__((ext_vector_type(4))) float f32x4;

// ws layout (bytes):
//       0 : WmT bf16 [256][256]   (131072)
//  131072 : proj f32 [256]        (1024)
//  132096 : At   f32 [100000]     (400000)
//  532096 : part2 float2[256]     (2048)
//  536192 : s1g  f32[256]         (1024)
//  537216 : s0g  f32[256]         (1024)
//  538240 : lse  f32              (4)

__device__ __forceinline__ float tanh_fast(float x) {
    float e = __expf(2.0f * x);
    return 1.0f - 2.0f / (e + 1.0f);
}

// ---------------------------------------------------------------- prep
__global__ __launch_bounds__(256) void k_prep(const float* __restrict__ Wm,
                                              const float* __restrict__ hc,
                                              const float* __restrict__ W1,
                                              __bf16* __restrict__ WmT,
                                              float* __restrict__ proj,
                                              float* __restrict__ s1g,
                                              float* __restrict__ s0g) {
    const int j = blockIdx.x;
    const int t = threadIdx.x;
    WmT[j * H_N + t] = (__bf16)Wm[t * H_N + j];   // B^T, k-contiguous
    __shared__ float red[H_N];
    red[t] = hc[t] * W1[j * H_N + t];
    __syncthreads();
    for (int off = 128; off > 0; off >>= 1) {
        if (t < off) red[t] += red[t + off];
        __syncthreads();
    }
    if (t == 0) proj[j] = red[0];
    if (j == 0) { s1g[t] = 0.0f; s0g[t] = 0.0f; }
}

// ---------------------------------------------------------------- fused At + LSE + ct partials
// 768 thr = 12 INDEPENDENT waves (no main-loop barriers). Each wave owns whole
// 16-row tiles. Software-pipelined per tile: ct x-loads hoisted above the jb
// MFMA loop (land under compute); A(t+1) raw prefetched into the regs freed by
// cvt, issued before the ct-FMA. Dual acc chains per jb block.
__global__ __launch_bounds__(768, 3) void k_at(const float* __restrict__ Mt,
                                               const __bf16* __restrict__ WmT,
                                               const float* __restrict__ proj,
                                               const float* __restrict__ V,
                                               float* __restrict__ At,
                                               float2* __restrict__ part2,
                                               float* __restrict__ s1g,
                                               float* __restrict__ s0g) {
    const int tid = threadIdx.x;
    const int lane = tid & 63;
    const int w = tid >> 6;     // 0..11
    const int l15 = lane & 15;
    const int lg = lane >> 4;   // 0..3

    struct SMem {
        __align__(16) char sB[131072];   // [n=256][k=256] bf16, XOR-swizzled
        float pj[256];
        float vj[256];
        float lsem[12], lses[12];
    };
    __shared__ SMem sm;

    // ---- B prologue (WmT L2-hot after k_prep)
    for (int g = tid; g < 8192; g += 768) {
        const int n = g >> 5;
        const int c = g & 31;
        const bf16x8 v = *(const bf16x8*)(WmT + n * H_N + c * 8);
        *(bf16x8*)(&sm.sB[(n * 512 + c * 16) ^ ((n & 7) << 4)]) = v;
    }
    if (tid < 256) { sm.pj[tid] = proj[tid]; sm.vj[tid] = V[tid]; }
    __syncthreads();   // ONLY barrier before the epilogue

    const int gw = blockIdx.x * 12 + w;   // global wave id
    float lm = -1e30f, ls = 0.0f;
    float s1a[4] = {0.f, 0.f, 0.f, 0.f};
    float s0a[4] = {0.f, 0.f, 0.f, 0.f};

    // A-raw staging for the CURRENT tile (prefetched one tile ahead)
    float4 R[16];
    auto loadA = [&](int tile) {
        const int tt = (tile < NT16) ? tile : (NT16 - 1);
        const float* arow = Mt + (size_t)(tt * 16 + l15) * H_N;
#pragma unroll
        for (int ks = 0; ks < 8; ++ks) {
            R[2 * ks]     = *(const float4*)(arow + 32 * ks + 8 * lg);
            R[2 * ks + 1] = *(const float4*)(arow + 32 * ks + 8 * lg + 4);
        }
    };

    loadA(gw);   // prologue load for the first tile

    for (int tile = gw; tile < NT16; tile += NWAVES) {
        // ---- cvt A(t) raw -> bf16 fragments (R dies here)
        bf16x8 af[8];
#pragma unroll
        for (int ks = 0; ks < 8; ++ks) {
            const float4 a0 = R[2 * ks], a1 = R[2 * ks + 1];
            af[ks][0] = (__bf16)a0.x; af[ks][1] = (__bf16)a0.y;
            af[ks][2] = (__bf16)a0.z; af[ks][3] = (__bf16)a0.w;
            af[ks][4] = (__bf16)a1.x; af[ks][5] = (__bf16)a1.y;
            af[ks][6] = (__bf16)a1.z; af[ks][7] = (__bf16)a1.w;
        }

        // ---- hoisted ct loads: land under the jb compute below
        const float* crow = Mt + (size_t)tile * 16 * H_N + lane * 4;
        float4 x[16];
#pragma unroll
        for (int r = 0; r < 16; ++r)
            x[r] = *(const float4*)(crow + (size_t)r * H_N);

        // ---- j-blocked MFMA: 16 col-blocks, dual acc chains per block
        float pacc[4] = {0.f, 0.f, 0.f, 0.f};
#pragma unroll 2
        for (int jb = 0; jb < 16; ++jb) {
            f32x4 accA = {0.f, 0.f, 0.f, 0.f};
            f32x4 accB = {0.f, 0.f, 0.f, 0.f};
            const int n = 16 * jb + l15;
            const int nb = n * 512;
            const int nswz = (n & 7) << 4;
#pragma unroll
            for (int ks = 0; ks < 4; ++ks) {
                const bf16x8 bfA = *(const bf16x8*)(
                    &sm.sB[nb + (((32 * ks + 8 * lg) * 2) ^ nswz)]);
                const bf16x8 bfB = *(const bf16x8*)(
                    &sm.sB[nb + (((32 * (ks + 4) + 8 * lg) * 2) ^ nswz)]);
                accA = __builtin_amdgcn_mfma_f32_16x16x32_bf16(af[ks], bfA, accA, 0, 0, 0);
                accB = __builtin_amdgcn_mfma_f32_16x16x32_bf16(af[ks + 4], bfB, accB, 0, 0, 0);
            }
            const float pjv = sm.pj[n], vjv = sm.vj[n];
#pragma unroll
            for (int i = 0; i < 4; ++i)
                pacc[i] += tanh_fast(accA[i] + accB[i] + pjv) * vjv;
        }

        // ---- row sums: butterfly over the 16 lanes of each lg group
        float p[4];
#pragma unroll
        for (int i = 0; i < 4; ++i) {
            float q = pacc[i];
            q += __shfl_xor(q, 1);
            q += __shfl_xor(q, 2);
            q += __shfl_xor(q, 4);
            q += __shfl_xor(q, 8);
            p[i] = q;    // all lanes in group hold row (4lg+i) total
        }
        if (l15 == 0) {
#pragma unroll
            for (int i = 0; i < 4; ++i) {
                const float at = p[i];
                At[tile * 16 + 4 * lg + i] = at;
                if (at > lm) { ls = ls * __expf(lm - at) + 1.0f; lm = at; }
                else ls += __expf(at - lm);
            }
        }

        // ---- prefetch A for the next tile (hides under ct-FMA + next cvt)
        loadA(tile + NWAVES);

        // ---- ct partials: x[] landed during jb; pure FMA now
#pragma unroll
        for (int r = 0; r < 16; ++r) {
            const float atr = __shfl(p[r & 3], 16 * (r >> 2));
            s1a[0] += atr * x[r].x; s1a[1] += atr * x[r].y;
            s1a[2] += atr * x[r].z; s1a[3] += atr * x[r].w;
            s0a[0] += x[r].x; s0a[1] += x[r].y;
            s0a[2] += x[r].z; s0a[3] += x[r].w;
        }
    }

    // ---- wave LSE partial -> shared
#pragma unroll
    for (int d = 1; d < 64; d <<= 1) {
        const float m2 = __shfl_xor(lm, d), s2 = __shfl_xor(ls, d);
        const float M = fmaxf(lm, m2);
        ls = ls * __expf(lm - M) + s2 * __expf(m2 - M);
        lm = M;
    }
    if (lane == 0) { sm.lsem[w] = lm; sm.lses[w] = ls; }

    // ---- block reduce of ct partials (reuse sB region)
    __syncthreads();
    float* red1 = (float*)&sm.sB[0];       // [12][256]
    float* red2 = (float*)&sm.sB[16384];   // [12][256]
#pragma unroll
    for (int q = 0; q < 4; ++q) {
        red1[w * 256 + lane * 4 + q] = s1a[q];
        red2[w * 256 + lane * 4 + q] = s0a[q];
    }
    __syncthreads();
    if (tid < 256) {
        float a = 0.f;
#pragma unroll
        for (int g = 0; g < 12; ++g) a += red1[g * 256 + tid];
        atomicAdd(&s1g[tid], a);
    } else if (tid < 512) {
        const int c = tid - 256;
        float a = 0.f;
#pragma unroll
        for (int g = 0; g < 12; ++g) a += red2[g * 256 + c];
        atomicAdd(&s0g[c], a);
    } else if (tid == 512) {
        float m = sm.lsem[0], s = sm.lses[0];
#pragma unroll
        for (int g = 1; g < 12; ++g) {
            const float m2 = sm.lsem[g], s2 = sm.lses[g];
            const float M = fmaxf(m, m2);
            s = s * __expf(m - M) + s2 * __expf(m2 - M);
            m = M;
        }
        part2[blockIdx.x] = make_float2(m, s);
    }
}

// ---------------------------------------------------------------- final: LSE + ct
__global__ __launch_bounds__(256) void k_final(const float2* __restrict__ part2,
                                               const float* __restrict__ s1g,
                                               const float* __restrict__ s0g,
                                               float* __restrict__ lse,
                                               float* __restrict__ out) {
    const int tid = threadIdx.x;
    __shared__ float ms[256], ss[256];
    const float2 p = part2[tid];
    ms[tid] = p.x; ss[tid] = p.y;
    __syncthreads();
    for (int off = 128; off > 0; off >>= 1) {
        if (tid < off) {
            const float m2 = ms[tid + off], s2 = ss[tid + off];
            const float M = fmaxf(ms[tid], m2);
            ss[tid] = ss[tid] * __expf(ms[tid] - M) + s2 * __expf(m2 - M);
            ms[tid] = M;
        }
        __syncthreads();
    }
    __shared__ float Ls;
    if (tid == 0) { Ls = ms[0] + logf(ss[0]); *lse = Ls; }
    __syncthreads();
    out[T_N + tid] = s1g[tid] - Ls * s0g[tid];
}

// ---------------------------------------------------------------- alphat = At - LSE
__global__ __launch_bounds__(256) void k_alpha(const float* __restrict__ At,
                                               const float* __restrict__ lse,
                                               float* __restrict__ out) {
    const float L = *lse;
    const int i4 = blockIdx.x * 256 + threadIdx.x;
    if (i4 < T_N / 4) {
        float4 a = *(const float4*)(At + i4 * 4);
        a.x -= L; a.y -= L; a.z -= L; a.w -= L;
        *(float4*)(out + i4 * 4) = a;
    }
}

// ----------------------------------------------------------------
extern "C" void kernel_launch(void* const* d_in, const int* in_sizes, int n_in,
                              void* d_out, int out_size, void* d_ws, size_t ws_size,
                              hipStream_t stream) {
    const float* inputs = (const float*)d_in[0];  // (T, H)
    const float* hc     = (const float*)d_in[1];  // (1, H)
    const float* Wm     = (const float*)d_in[2];  // (H, H)
    const float* V      = (const float*)d_in[3];  // (H, 1)
    const float* W1     = (const float*)d_in[4];  // (H, H)
    float* out = (float*)d_out;                   // [alphat (T) | ct (H)]

    char* ws = (char*)d_ws;
    __bf16* WmT  = (__bf16*)ws;
    float* proj  = (float*)(ws + 131072);
    float* At    = (float*)(ws + 132096);
    float2* p2   = (float2*)(ws + 532096);
    float* s1g   = (float*)(ws + 536192);
    float* s0g   = (float*)(ws + 537216);
    float* lse   = (float*)(ws + 538240);

    k_prep<<<256, 256, 0, stream>>>(Wm, hc, W1, WmT, proj, s1g, s0g);
    k_at<<<NB_AT, 768, 0, stream>>>(inputs, WmT, proj, V, At, p2, s1g, s0g);
    k_final<<<1, 256, 0, stream>>>(p2, s1g, s0g, lse, out);
    k_alpha<<<98, 256, 0, stream>>>(At, lse, out);
}

// Round 15
// 56.562 us; speedup vs baseline: 6.3384x; 1.0532x over previous
//
#include <hip/hip_runtime.h>
#include <math.h>

#define T_N 100000
#define H_N 256
#define NT32 (T_N / 32)        // 3125 32-row tiles, exact
#define NB_AT 256              // k_at grid
#define WPB 13                 // waves per block
#define NTHR (WPB * 64)        // 832 threads

typedef __attribute__((ext_vector_type(8))) __bf16 bf16x8;
typedef __attribute__((ext_vector_type(4))) float f32x4;

// ws layout (bytes):
//       0 : WmT bf16 [256][256]   (131072)
//  131072 : proj f32 [256]        (1024)
//  132096 : At   f32 [100000]     (400000)
//  532096 : part2 float2[256]     (2048)
//  536192 : s1g  f32[256]         (1024)
//  537216 : s0g  f32[256]         (1024)
//  538240 : lse  f32              (4)

__device__ __forceinline__ float tanh_fast(float x) {
    float e = __expf(2.0f * x);
    return 1.0f - 2.0f / (e + 1.0f);
}

// ---------------------------------------------------------------- prep
__global__ __launch_bounds__(256) void k_prep(const float* __restrict__ Wm,
                                              const float* __restrict__ hc,
                                              const float* __restrict__ W1,
                                              __bf16* __restrict__ WmT,
                                              float* __restrict__ proj,
                                              float* __restrict__ s1g,
                                              float* __restrict__ s0g) {
    const int j = blockIdx.x;
    const int t = threadIdx.x;
    WmT[j * H_N + t] = (__bf16)Wm[t * H_N + j];   // B^T, k-contiguous
    __shared__ float red[H_N];
    red[t] = hc[t] * W1[j * H_N + t];
    __syncthreads();
    for (int off = 128; off > 0; off >>= 1) {
        if (t < off) red[t] += red[t + off];
        __syncthreads();
    }
    if (t == 0) proj[j] = red[0];
    if (j == 0) { s1g[t] = 0.0f; s0g[t] = 0.0f; }
}

// ---------------------------------------------------------------- fused At + LSE + ct partials
// 832 thr = 13 waves; 3328 waves total for 3125 32-row tiles -> EXACTLY ONE
// tile per wave (203 idle), zero multi-round imbalance, no main-loop barriers.
// Per wave: A-frags for 2 row-groups direct from global (64 VGPR bf16);
// jb loop over 16 col-blocks with B ds_reads SHARED by both row-groups
// (halves LDS traffic/row); 4 independent MFMA chains. ct partials from the
// L2-hot fp32 re-read after af[] dies. LSE online per lane.
__global__ __launch_bounds__(NTHR, 4) void k_at(const float* __restrict__ Mt,
                                                const __bf16* __restrict__ WmT,
                                                const float* __restrict__ proj,
                                                const float* __restrict__ V,
                                                float* __restrict__ At,
                                                float2* __restrict__ part2,
                                                float* __restrict__ s1g,
                                                float* __restrict__ s0g) {
    const int tid = threadIdx.x;
    const int lane = tid & 63;
    const int w = tid >> 6;     // 0..12
    const int l15 = lane & 15;
    const int lg = lane >> 4;   // 0..3

    struct SMem {
        __align__(16) char sB[131072];   // [n=256][k=256] bf16, XOR-swizzled
        float pj[256];
        float vj[256];
        float lsem[WPB], lses[WPB];
    };
    __shared__ SMem sm;

    // ---- B prologue (WmT L2-hot after k_prep)
    for (int g = tid; g < 8192; g += NTHR) {
        const int n = g >> 5;
        const int c = g & 31;
        const bf16x8 v = *(const bf16x8*)(WmT + n * H_N + c * 8);
        *(bf16x8*)(&sm.sB[(n * 512 + c * 16) ^ ((n & 7) << 4)]) = v;
    }
    if (tid < 256) { sm.pj[tid] = proj[tid]; sm.vj[tid] = V[tid]; }
    __syncthreads();

    const int gw = blockIdx.x * WPB + w;   // global wave id = tile id
    float lm = -1e30f, ls = 0.0f;
    float s1a[4] = {0.f, 0.f, 0.f, 0.f};
    float s0a[4] = {0.f, 0.f, 0.f, 0.f};

    if (gw < NT32) {
        const int t0 = gw * 32;
        const float* arow0 = Mt + (size_t)(t0 + l15) * H_N;
        const float* arow1 = Mt + (size_t)(t0 + 16 + l15) * H_N;

        // ---- A fragments for both row-groups (cvt at load; 64 VGPR total)
        bf16x8 af0[8], af1[8];
#pragma unroll
        for (int ks = 0; ks < 8; ++ks) {
            const float4 a0 = *(const float4*)(arow0 + 32 * ks + 8 * lg);
            const float4 a1 = *(const float4*)(arow0 + 32 * ks + 8 * lg + 4);
            af0[ks][0] = (__bf16)a0.x; af0[ks][1] = (__bf16)a0.y;
            af0[ks][2] = (__bf16)a0.z; af0[ks][3] = (__bf16)a0.w;
            af0[ks][4] = (__bf16)a1.x; af0[ks][5] = (__bf16)a1.y;
            af0[ks][6] = (__bf16)a1.z; af0[ks][7] = (__bf16)a1.w;
            const float4 b0 = *(const float4*)(arow1 + 32 * ks + 8 * lg);
            const float4 b1 = *(const float4*)(arow1 + 32 * ks + 8 * lg + 4);
            af1[ks][0] = (__bf16)b0.x; af1[ks][1] = (__bf16)b0.y;
            af1[ks][2] = (__bf16)b0.z; af1[ks][3] = (__bf16)b0.w;
            af1[ks][4] = (__bf16)b1.x; af1[ks][5] = (__bf16)b1.y;
            af1[ks][6] = (__bf16)b1.z; af1[ks][7] = (__bf16)b1.w;
        }

        // ---- jb loop: 16 col-blocks; B-reads shared by both row-groups
        float pacc0[4] = {0.f, 0.f, 0.f, 0.f};
        float pacc1[4] = {0.f, 0.f, 0.f, 0.f};
#pragma unroll 1
        for (int jb = 0; jb < 16; ++jb) {
            f32x4 a0A = {0.f, 0.f, 0.f, 0.f}, a0B = {0.f, 0.f, 0.f, 0.f};
            f32x4 a1A = {0.f, 0.f, 0.f, 0.f}, a1B = {0.f, 0.f, 0.f, 0.f};
            const int n = 16 * jb + l15;
            const int nb = n * 512;
            const int nswz = (n & 7) << 4;
#pragma unroll
            for (int ks = 0; ks < 4; ++ks) {
                const bf16x8 bfA = *(const bf16x8*)(
                    &sm.sB[nb + (((32 * ks + 8 * lg) * 2) ^ nswz)]);
                const bf16x8 bfB = *(const bf16x8*)(
                    &sm.sB[nb + (((32 * (ks + 4) + 8 * lg) * 2) ^ nswz)]);
                a0A = __builtin_amdgcn_mfma_f32_16x16x32_bf16(af0[ks], bfA, a0A, 0, 0, 0);
                a1A = __builtin_amdgcn_mfma_f32_16x16x32_bf16(af1[ks], bfA, a1A, 0, 0, 0);
                a0B = __builtin_amdgcn_mfma_f32_16x16x32_bf16(af0[ks + 4], bfB, a0B, 0, 0, 0);
                a1B = __builtin_amdgcn_mfma_f32_16x16x32_bf16(af1[ks + 4], bfB, a1B, 0, 0, 0);
            }
            const float pjv = sm.pj[n], vjv = sm.vj[n];
#pragma unroll
            for (int i = 0; i < 4; ++i) {
                pacc0[i] += tanh_fast(a0A[i] + a0B[i] + pjv) * vjv;
                pacc1[i] += tanh_fast(a1A[i] + a1B[i] + pjv) * vjv;
            }
        }

        // ---- row sums: butterfly over the 16 lanes of each lg group
        float p0[4], p1[4];
#pragma unroll
        for (int i = 0; i < 4; ++i) {
            float q0 = pacc0[i], q1 = pacc1[i];
            q0 += __shfl_xor(q0, 1); q1 += __shfl_xor(q1, 1);
            q0 += __shfl_xor(q0, 2); q1 += __shfl_xor(q1, 2);
            q0 += __shfl_xor(q0, 4); q1 += __shfl_xor(q1, 4);
            q0 += __shfl_xor(q0, 8); q1 += __shfl_xor(q1, 8);
            p0[i] = q0; p1[i] = q1;
        }
        if (l15 == 0) {
#pragma unroll
            for (int i = 0; i < 4; ++i) {
                const float a0v = p0[i], a1v = p1[i];
                At[t0 + 4 * lg + i] = a0v;
                At[t0 + 16 + 4 * lg + i] = a1v;
                if (a0v > lm) { ls = ls * __expf(lm - a0v) + 1.0f; lm = a0v; }
                else ls += __expf(a0v - lm);
                if (a1v > lm) { ls = ls * __expf(lm - a1v) + 1.0f; lm = a1v; }
                else ls += __expf(a1v - lm);
            }
        }

        // ---- ct partials: re-read fp32 tile (L2-hot; af[] regs now free)
        const float* crow = Mt + (size_t)t0 * H_N + lane * 4;
        {
            float4 x[16];
#pragma unroll
            for (int r = 0; r < 16; ++r)
                x[r] = *(const float4*)(crow + (size_t)r * H_N);
#pragma unroll
            for (int r = 0; r < 16; ++r) {
                const float atr = __shfl(p0[r & 3], 16 * (r >> 2));
                s1a[0] += atr * x[r].x; s1a[1] += atr * x[r].y;
                s1a[2] += atr * x[r].z; s1a[3] += atr * x[r].w;
                s0a[0] += x[r].x; s0a[1] += x[r].y;
                s0a[2] += x[r].z; s0a[3] += x[r].w;
            }
#pragma unroll
            for (int r = 0; r < 16; ++r)
                x[r] = *(const float4*)(crow + (size_t)(16 + r) * H_N);
#pragma unroll
            for (int r = 0; r < 16; ++r) {
                const float atr = __shfl(p1[r & 3], 16 * (r >> 2));
                s1a[0] += atr * x[r].x; s1a[1] += atr * x[r].y;
                s1a[2] += atr * x[r].z; s1a[3] += atr * x[r].w;
                s0a[0] += x[r].x; s0a[1] += x[r].y;
                s0a[2] += x[r].z; s0a[3] += x[r].w;
            }
        }
    }

    // ---- wave LSE partial -> shared
#pragma unroll
    for (int d = 1; d < 64; d <<= 1) {
        const float m2 = __shfl_xor(lm, d), s2 = __shfl_xor(ls, d);
        const float M = fmaxf(lm, m2);
        ls = ls * __expf(lm - M) + s2 * __expf(m2 - M);
        lm = M;
    }
    if (lane == 0) { sm.lsem[w] = lm; sm.lses[w] = ls; }

    // ---- block reduce of ct partials (reuse sB region)
    __syncthreads();
    float* red1 = (float*)&sm.sB[0];       // [13][256]
    float* red2 = (float*)&sm.sB[65536];   // [13][256]
#pragma unroll
    for (int q = 0; q < 4; ++q) {
        red1[w * 256 + lane * 4 + q] = s1a[q];
        red2[w * 256 + lane * 4 + q] = s0a[q];
    }
    __syncthreads();
    if (tid < 256) {
        float a = 0.f;
#pragma unroll
        for (int g = 0; g < WPB; ++g) a += red1[g * 256 + tid];
        atomicAdd(&s1g[tid], a);
    } else if (tid < 512) {
        const int c = tid - 256;
        float a = 0.f;
#pragma unroll
        for (int g = 0; g < WPB; ++g) a += red2[g * 256 + c];
        atomicAdd(&s0g[c], a);
    } else if (tid == 512) {
        float m = sm.lsem[0], s = sm.lses[0];
#pragma unroll
        for (int g = 1; g < WPB; ++g) {
            const float m2 = sm.lsem[g], s2 = sm.lses[g];
            const float M = fmaxf(m, m2);
            s = s * __expf(m - M) + s2 * __expf(m2 - M);
            m = M;
        }
        part2[blockIdx.x] = make_float2(m, s);
    }
}

// ---------------------------------------------------------------- final: LSE + ct
__global__ __launch_bounds__(256) void k_final(const float2* __restrict__ part2,
                                               const float* __restrict__ s1g,
                                               const float* __restrict__ s0g,
                                               float* __restrict__ lse,
                                               float* __restrict__ out) {
    const int tid = threadIdx.x;
    __shared__ float ms[256], ss[256];
    const float2 p = part2[tid];
    ms[tid] = p.x; ss[tid] = p.y;
    __syncthreads();
    for (int off = 128; off > 0; off >>= 1) {
        if (tid < off) {
            const float m2 = ms[tid + off], s2 = ss[tid + off];
            const float M = fmaxf(ms[tid], m2);
            ss[tid] = ss[tid] * __expf(ms[tid] - M) + s2 * __expf(m2 - M);
            ms[tid] = M;
        }
        __syncthreads();
    }
    __shared__ float Ls;
    if (tid == 0) { Ls = ms[0] + logf(ss[0]); *lse = Ls; }
    __syncthreads();
    out[T_N + tid] = s1g[tid] - Ls * s0g[tid];
}

// ---------------------------------------------------------------- alphat = At - LSE
__global__ __launch_bounds__(256) void k_alpha(const float* __restrict__ At,
                                               const float* __restrict__ lse,
                                               float* __restrict__ out) {
    const float L = *lse;
    const int i4 = blockIdx.x * 256 + threadIdx.x;
    if (i4 < T_N / 4) {
        float4 a = *(const float4*)(At + i4 * 4);
        a.x -= L; a.y -= L; a.z -= L; a.w -= L;
        *(float4*)(out + i4 * 4) = a;
    }
}

// ----------------------------------------------------------------
extern "C" void kernel_launch(void* const* d_in, const int* in_sizes, int n_in,
                              void* d_out, int out_size, void* d_ws, size_t ws_size,
                              hipStream_t stream) {
    const float* inputs = (const float*)d_in[0];  // (T, H)
    const float* hc     = (const float*)d_in[1];  // (1, H)
    const float* Wm     = (const float*)d_in[2];  // (H, H)
    const float* V      = (const float*)d_in[3];  // (H, 1)
    const float* W1     = (const float*)d_in[4];  // (H, H)
    float* out = (float*)d_out;                   // [alphat (T) | ct (H)]

    char* ws = (char*)d_ws;
    __bf16* WmT  = (__bf16*)ws;
    float* proj  = (float*)(ws + 131072);
    float* At    = (float*)(ws + 132096);
    float2* p2   = (float2*)(ws + 532096);
    float* s1g   = (float*)(ws + 536192);
    float* s0g   = (float*)(ws + 537216);
    float* lse   = (float*)(ws + 538240);

    k_prep<<<256, 256, 0, stream>>>(Wm, hc, W1, WmT, proj, s1g, s0g);
    k_at<<<NB_AT, NTHR, 0, stream>>>(inputs, WmT, proj, V, At, p2, s1g, s0g);
    k_final<<<1, 256, 0, stream>>>(p2, s1g, s0g, lse, out);
    k_alpha<<<98, 256, 0, stream>>>(At, lse, out);
}